// Round 1
// baseline (407.146 us; speedup 1.0000x reference)
//
#include <hip/hip_runtime.h>
#include <math.h>

// Problem constants
#define B_   32
#define L_   200
#define DIN_ 256
#define D_   64
#define PL_  8

// ws layout (float offsets)
#define OFF_WT    0         // 3*16384 transposed weights [i][d]
#define OFF_Q     49152     // B*L*D
#define OFF_NQ    458752
#define OFF_Z     868352
#define OFF_V     1277952
#define OFF_SZ    1687552   // B*L
#define OFF_SV    1693952
#define OFF_SNQ   1700352
#define OFF_PZL   1706752   // B*D
#define OFF_PSL   1708800   // B*D*D
#define OFF_PNAM  1839872   // B*D*D
#define OFF_MPS2  1970944   // B
#define OFF_COL   1970976   // B*L
#define OFF_H     1977376
#define OFF_C     1983776
#define OFF_CA    1990176
#define OFF_CB    1996576
#define OFF_CC    2002976
#define OFF_SY    2009376   // B
#define OFF_SY2   2009408   // B

__device__ __forceinline__ float wsum(float x){
#pragma unroll
  for (int o = 32; o > 0; o >>= 1) x += __shfl_xor(x, o, 64);
  return x;
}
__device__ __forceinline__ float eluf(float x){ return x > 0.f ? x : expm1f(x); }

// K0: transpose Wq,Wk,Wv [64,256] -> [256,64]
__global__ __launch_bounds__(256) void k_transpose(const float* __restrict__ Wq,
    const float* __restrict__ Wk, const float* __restrict__ Wv, float* __restrict__ wt){
  int idx = blockIdx.x*256 + threadIdx.x;
  if (idx >= 3*16384) return;
  int m = idx >> 14, r = idx & 16383, i = r >> 6, d = r & 63;
  const float* W = (m==0) ? Wq : ((m==1) ? Wk : Wv);
  wt[m*16384 + i*64 + d] = W[d*256 + i];
}

// K1: q,z,v GEMMs + per-row stats. 16 rows/block, 256 thr (wave g owns rows g+4j)
__global__ __launch_bounds__(256) void k_qzv(const float* __restrict__ x, const float* __restrict__ Wt,
    const float* __restrict__ bq, const float* __restrict__ bk, const float* __restrict__ bv,
    float* __restrict__ q, float* __restrict__ nq, float* __restrict__ z, float* __restrict__ v,
    float* __restrict__ sz, float* __restrict__ sv, float* __restrict__ snq){
  __shared__ float xs[16*256];
  int row0 = blockIdx.x * 16;
  int tid = threadIdx.x, d = tid & 63, g = tid >> 6;
  for (int k = tid; k < 4096; k += 256) xs[k] = x[row0*256 + k];
  __syncthreads();
  const float* Wtq = Wt;
  const float* Wtk = Wt + 16384;
  const float* Wtv = Wt + 32768;
  float aq[4] = {0,0,0,0}, ak[4] = {0,0,0,0}, av[4] = {0,0,0,0};
  for (int i = 0; i < 256; i++){
    float wq = Wtq[i*64+d], wk = Wtk[i*64+d], wv = Wtv[i*64+d];
#pragma unroll
    for (int j = 0; j < 4; j++){
      float xv = xs[(g+4*j)*256 + i];
      aq[j] = fmaf(xv, wq, aq[j]);
      ak[j] = fmaf(xv, wk, ak[j]);
      av[j] = fmaf(xv, wv, av[j]);
    }
  }
  float bqd = bq[d], bkd = bk[d], bvd = bv[d];
#pragma unroll
  for (int j = 0; j < 4; j++){
    int r = row0 + g + 4*j;
    float qv = eluf(aq[j] + bqd);
    float zv = eluf(ak[j] + bkd);
    float vv = av[j] + bvd;
    float sq2 = wsum(qv*qv);
    float sq1 = wsum(qv);
    float szv = wsum(zv);
    float svv = wsum(vv);
    float inv = 1.f / (sqrtf(sq2) + 1e-8f);
    q[r*64+d] = qv; nq[r*64+d] = qv*inv; z[r*64+d] = zv; v[r*64+d] = vv;
    if (d == 0){ sz[r] = szv; sv[r] = svv; snq[r] = sq1*inv; }
  }
}

// K2: prompts P,S + user state -> PzL, PsL, mps2, pNAM(masked). 1 block per b.
__global__ __launch_bounds__(256) void k_prompt(const float* __restrict__ P, const float* __restrict__ Sp,
    const int* __restrict__ uid, const float* __restrict__ prev_z, const float* __restrict__ prev_s,
    const float* __restrict__ Wt, const float* __restrict__ bk, const float* __restrict__ bv,
    float* __restrict__ PzL, float* __restrict__ PsL, float* __restrict__ mps2, float* __restrict__ pNAM){
  int b = blockIdx.x, tid = threadIdx.x;
  __shared__ float xP[2048], xS[2048];
  __shared__ float zP[512], vP[512], zS[512], vS[512];
  __shared__ float red[8];
  __shared__ float facs;
  for (int k = tid; k < 2048; k += 256){ xP[k] = P[b*2048 + k]; xS[k] = Sp[b*2048 + k]; }
  __syncthreads();
  const float* Wtk = Wt + 16384;
  const float* Wtv = Wt + 32768;
  for (int idx = tid; idx < 512; idx += 256){
    int t = idx >> 6, d = idx & 63;
    float aPk=0,aPv=0,aSk=0,aSv=0;
    for (int i = 0; i < 256; i++){
      float wk = Wtk[i*64+d], wv = Wtv[i*64+d];
      float xp = xP[t*256+i], xq = xS[t*256+i];
      aPk = fmaf(xp,wk,aPk); aPv = fmaf(xp,wv,aPv);
      aSk = fmaf(xq,wk,aSk); aSv = fmaf(xq,wv,aSv);
    }
    zP[idx] = eluf(aPk + bk[d]); vP[idx] = aPv + bv[d];
    zS[idx] = eluf(aSk + bk[d]); vS[idx] = aSv + bv[d];
  }
  __syncthreads();
  // S_P = sum_t zP vP^T (only last cumsum step needed); same for S prompt
  float spv[16], ssv[16];
  float l1=0.f, l2=0.f, l3=0.f, l4=0.f;
  int p = tid >> 2, q0 = (tid & 3) * 16;
#pragma unroll
  for (int k = 0; k < 16; k++){
    int qq = q0 + k;
    float sp = 0.f, ss = 0.f;
#pragma unroll
    for (int t = 0; t < 8; t++){
      sp = fmaf(zP[t*64+p], vP[t*64+qq], sp);
      ss = fmaf(zS[t*64+p], vS[t*64+qq], ss);
    }
    spv[k] = sp; ssv[k] = ss;
    l1 += sp; l2 += sp*sp; l3 += ss; l4 += ss*ss;
  }
  float sums[4] = {l1,l2,l3,l4};
  float tot[4];
  for (int r = 0; r < 4; r++){
    float val = wsum(sums[r]);
    if ((tid & 63) == 0) red[tid >> 6] = val;
    __syncthreads();
    tot[r] = red[0] + red[1] + red[2] + red[3];
    __syncthreads();
  }
  float mP = tot[0] * (1.f/4096.f);
  float varP = tot[1] * (1.f/4096.f) - mP*mP;
  float invP = rsqrtf(varP + 1e-5f);
  float mS = tot[2] * (1.f/4096.f);
  float varS = tot[3] * (1.f/4096.f) - mS*mS;
  float invS = rsqrtf(varS + 1e-5f);
  if (tid == 0) mps2[b] = varP * invP * invP;  // E[PsL^2]
  int u = uid[b];
  if (tid < 64){
    int d = tid;
    float zc = 0.f, zs = 0.f;
#pragma unroll
    for (int t = 0; t < 8; t++){ zc += zP[t*64+d]; zs += zS[t*64+d]; }
    float s1 = wsum(zc), s2 = wsum(zc*zc);
    float mz = s1*(1.f/64.f), vz = s2*(1.f/64.f) - mz*mz;
    PzL[b*64+d] = (zc - mz) * rsqrtf(vz + 1e-5f);
    float t1 = wsum(zs), t2 = wsum(zs*zs);
    float mzs = t1*(1.f/64.f), vzs = t2*(1.f/64.f) - mzs*mzs;
    float szl = (zs - mzs) * rsqrtf(vzs + 1e-5f);
    float pzv = prev_z[u*64 + d];
    float zu = pzv + szl;
    float zl2 = wsum(zu*zu);
    float psumv = wsum(pzv);
    float fac = ((psumv != 0.f) ? 1.f : 0.f) / (sqrtf(zl2) + 1e-8f);
    if (d == 0) facs = fac;
  }
  __syncthreads();
  float fac = facs;
  const float* psrow = prev_s + (size_t)u * 4096;
#pragma unroll
  for (int k = 0; k < 16; k++){
    int o = p*64 + q0 + k;
    float psl = (spv[k] - mP) * invP;
    PsL[b*4096 + o] = psl;
    float su = psrow[o] + (ssv[k] - mS) * invS;
    pNAM[b*4096 + o] = su * fac;
  }
}

// K3a: per (b,l): colsum_l = sum_{t<=l}(z_t.z_l)(v_t.v_l), h_l = diag term, c_l = z_l^T PsL v_l
__global__ __launch_bounds__(256) void k_gram(const float* __restrict__ z, const float* __restrict__ v,
    const float* __restrict__ PsL, float* __restrict__ colsum, float* __restrict__ harr, float* __restrict__ carr){
  int b = blockIdx.x / 7, lt = blockIdx.x % 7;
  int l0 = lt * 32;
  int tid = threadIdx.x, lane = tid & 63, g = tid >> 6;
  __shared__ __align__(16) float zl[32*64];
  __shared__ __align__(16) float vl[32*64];
  const float* zb = z + b * (L_*D_);
  const float* vb = v + b * (L_*D_);
  for (int k = tid; k < 2048; k += 256){
    int l = l0 + (k >> 6);
    zl[k] = (l < L_) ? zb[l*64 + (k & 63)] : 0.f;
    vl[k] = (l < L_) ? vb[l*64 + (k & 63)] : 0.f;
  }
  __syncthreads();
  for (int j = 0; j < 8; j++){
    int li = g + 4*j;
    int l = l0 + li;
    if (l >= L_) continue;
    // c_l
    float wacc = 0.f;
    const float* psr = PsL + b*4096 + lane*64;
#pragma unroll
    for (int qq = 0; qq < 64; qq += 4){
      float4 p4 = *(const float4*)(psr + qq);
      float4 v4 = *(const float4*)(&vl[li*64 + qq]);
      wacc += p4.x*v4.x + p4.y*v4.y + p4.z*v4.z + p4.w*v4.w;
    }
    float c = wsum(zl[li*64 + lane] * wacc);
    // colsum + h
    float ps_acc = 0.f, hval = 0.f;
    for (int tbase = 0; tbase <= l; tbase += 64){
      int t = tbase + lane;
      float pz = 0.f, pv = 0.f;
      if (t <= l){
        const float* zr = zb + t*64;
        const float* vr = vb + t*64;
#pragma unroll
        for (int dd = 0; dd < 64; dd += 4){
          float4 za = *(const float4*)(zr + dd);
          float4 zc4 = *(const float4*)(&zl[li*64 + dd]);
          pz += za.x*zc4.x + za.y*zc4.y + za.z*zc4.z + za.w*zc4.w;
          float4 va = *(const float4*)(vr + dd);
          float4 vc4 = *(const float4*)(&vl[li*64 + dd]);
          pv += va.x*vc4.x + va.y*vc4.y + va.z*vc4.z + va.w*vc4.w;
        }
      }
      float prod = pz * pv;
      ps_acc += prod;
      if ((l & ~63) == tbase) hval = __shfl(prod, l & 63, 64);
    }
    float cs = wsum(ps_acc);
    if (lane == 0){
      colsum[b*L_ + l] = cs;
      harr[b*L_ + l]  = hval;
      carr[b*L_ + l]  = c;
    }
  }
}

// K3b: per-b sequential scan over l: LN stats of S, z-cumsum LN, coefficients, std partials
__global__ __launch_bounds__(64) void k_scan(const float* __restrict__ z, const float* __restrict__ q,
    const float* __restrict__ sz, const float* __restrict__ sv, const float* __restrict__ snq,
    const float* __restrict__ colsum, const float* __restrict__ harr, const float* __restrict__ carr,
    const float* __restrict__ PzL, const float* __restrict__ mps2,
    float* __restrict__ cA, float* __restrict__ cB, float* __restrict__ cC,
    float* __restrict__ Sy, float* __restrict__ Sy2){
  int b = blockIdx.x, d = threadIdx.x;
  float Zc = 0.f, Msum = 0.f, R = 0.f, C = 0.f, ys = 0.f, ys2 = 0.f;
  float pzl = PzL[b*64+d];
  float mp2 = mps2[b];
  const float* zb = z + b*12800;
  const float* qb = q + b*12800;
  for (int l = 0; l < 200; l++){
    int row = b*200 + l;
    Zc += zb[l*64+d];
    float s1 = wsum(Zc), s2 = wsum(Zc*Zc);
    float mz = s1*(1.f/64.f), vz = s2*(1.f/64.f) - mz*mz;
    float zf = (Zc - mz) * rsqrtf(vz + 1e-5f) + pzl;
    float zl2 = wsum(zf*zf);
    float a = sqrtf(zl2) + 1e-8f;
    Msum = fmaf(sz[row], sv[row], Msum);
    float m = Msum * (1.f/4096.f);
    R += 2.f*colsum[row] - harr[row];
    float var = R*(1.f/4096.f) - m*m;
    float inv = rsqrtf(var + 1e-5f);
    C += carr[row];
    float varT = inv*inv*var + 2.f*inv*C*(1.f/4096.f) + mp2;
    float invT = rsqrtf(varT + 1e-5f*a*a);
    if (d == 0){
      cA[row] = invT*inv;
      cB[row] = invT*inv*m*snq[row];
      cC[row] = invT;
    }
    float y = qb[l*64+d] / fmaxf(zf, 1e-6f);
    ys += y;
    ys2 = fmaf(y, y, ys2);
  }
  ys = wsum(ys); ys2 = wsum(ys2);
  if (d == 0){ Sy[b] = ys; Sy2[b] = ys2; }
}

// K4: per (b,l): causal linear attention core + PsL/pNAM GEMVs + final LN
__global__ __launch_bounds__(64) void k_final(const float* __restrict__ nq, const float* __restrict__ z,
    const float* __restrict__ v, const float* __restrict__ PsL, const float* __restrict__ pNAM,
    const float* __restrict__ cA, const float* __restrict__ cB, const float* __restrict__ cC,
    float* __restrict__ out){
  int row = blockIdx.x;
  int b = row / 200, l = row % 200;
  int lane = threadIdx.x;
  __shared__ __align__(16) float nqs[64];
  __shared__ float sc[64];
  nqs[lane] = nq[row*64 + lane];
  __syncthreads();
  const float* zb = z + b*12800;
  const float* vb = v + b*12800;
  float acc = 0.f;
  for (int tbase = 0; tbase <= l; tbase += 64){
    int t = tbase + lane;
    float s = 0.f;
    if (t <= l){
      const float* zr = zb + t*64;
#pragma unroll
      for (int dd = 0; dd < 64; dd += 4){
        float4 za = *(const float4*)(zr + dd);
        s += nqs[dd]*za.x + nqs[dd+1]*za.y + nqs[dd+2]*za.z + nqs[dd+3]*za.w;
      }
    }
    __syncthreads();
    sc[lane] = s;
    __syncthreads();
    int tmax = min(63, l - tbase);
    for (int tt = 0; tt <= tmax; tt++)
      acc = fmaf(sc[tt], vb[(tbase+tt)*64 + lane], acc);
  }
  float t1 = 0.f, t2 = 0.f;
  const float* ps = PsL + b*4096;
  const float* pn = pNAM + b*4096;
  for (int p = 0; p < 64; p++){
    float np = nqs[p];
    t1 = fmaf(np, ps[p*64 + lane], t1);
    t2 = fmaf(np, pn[p*64 + lane], t2);
  }
  float NA1 = cA[row]*acc - cB[row] + cC[row]*t1 + t2;
  float s1 = wsum(NA1), s2 = wsum(NA1*NA1);
  float m = s1*(1.f/64.f), var = s2*(1.f/64.f) - m*m;
  out[row*64 + lane] = (NA1 - m) * rsqrtf(var + 1e-5f);
}

// K5: finalize std (ddof=1) over all B*L*D elements
__global__ __launch_bounds__(64) void k_std(const float* __restrict__ Sy, const float* __restrict__ Sy2,
    float* __restrict__ out){
  int lane = threadIdx.x;
  float a = (lane < 32) ? Sy[lane] : 0.f;
  float b2 = (lane < 32) ? Sy2[lane] : 0.f;
  a = wsum(a); b2 = wsum(b2);
  if (lane == 0){
    const float N = 409600.f;
    float var = (b2 - a*a/N) / (N - 1.f);
    out[409600] = sqrtf(fmaxf(var, 0.f));
  }
}

extern "C" void kernel_launch(void* const* d_in, const int* in_sizes, int n_in,
                              void* d_out, int out_size, void* d_ws, size_t ws_size,
                              hipStream_t stream) {
  const int*   uid    = (const int*)d_in[0];
  const float* seqs   = (const float*)d_in[1];
  const float* P      = (const float*)d_in[2];
  const float* S      = (const float*)d_in[3];
  const float* prev_z = (const float*)d_in[4];
  const float* prev_s = (const float*)d_in[5];
  const float* Wq     = (const float*)d_in[6];
  const float* bq     = (const float*)d_in[7];
  const float* Wk     = (const float*)d_in[8];
  const float* bk     = (const float*)d_in[9];
  const float* Wv     = (const float*)d_in[10];
  const float* bv     = (const float*)d_in[11];
  float* w   = (float*)d_ws;
  float* out = (float*)d_out;

  k_transpose<<<192, 256, 0, stream>>>(Wq, Wk, Wv, w + OFF_WT);
  k_qzv<<<400, 256, 0, stream>>>(seqs, w + OFF_WT, bq, bk, bv,
      w + OFF_Q, w + OFF_NQ, w + OFF_Z, w + OFF_V, w + OFF_SZ, w + OFF_SV, w + OFF_SNQ);
  k_prompt<<<32, 256, 0, stream>>>(P, S, uid, prev_z, prev_s, w + OFF_WT, bk, bv,
      w + OFF_PZL, w + OFF_PSL, w + OFF_MPS2, w + OFF_PNAM);
  k_gram<<<224, 256, 0, stream>>>(w + OFF_Z, w + OFF_V, w + OFF_PSL,
      w + OFF_COL, w + OFF_H, w + OFF_C);
  k_scan<<<32, 64, 0, stream>>>(w + OFF_Z, w + OFF_Q, w + OFF_SZ, w + OFF_SV, w + OFF_SNQ,
      w + OFF_COL, w + OFF_H, w + OFF_C, w + OFF_PZL, w + OFF_MPS2,
      w + OFF_CA, w + OFF_CB, w + OFF_CC, w + OFF_SY, w + OFF_SY2);
  k_final<<<6400, 64, 0, stream>>>(w + OFF_NQ, w + OFF_Z, w + OFF_V, w + OFF_PSL, w + OFF_PNAM,
      w + OFF_CA, w + OFF_CB, w + OFF_CC, out);
  k_std<<<1, 64, 0, stream>>>(w + OFF_SY, w + OFF_SY2, out);
}

// Round 2
// 214.194 us; speedup vs baseline: 1.9008x; 1.9008x over previous
//
#include <hip/hip_runtime.h>
#include <math.h>

// Problem constants
#define B_   32
#define L_   200
#define DIN_ 256
#define D_   64
#define PL_  8

// ws layout (float offsets)
#define OFF_WT    0         // 3*16384 transposed weights [i][d]
#define OFF_Q     49152     // B*L*D
#define OFF_NQ    458752
#define OFF_Z     868352
#define OFF_V     1277952
#define OFF_SZ    1687552   // B*L
#define OFF_SV    1693952
#define OFF_SNQ   1700352
#define OFF_PZL   1706752   // B*D
#define OFF_PSL   1708800   // B*D*D
#define OFF_PNAM  1839872   // B*D*D
#define OFF_MPS2  1970944   // B
#define OFF_COL   1970976   // B*L
#define OFF_H     1977376
#define OFF_C     1983776
#define OFF_CM    1990176   // B*L prefix of sz*sv
#define OFF_CR    1996576   // B*L prefix of 2*col-h
#define OFF_CCP   2002976   // B*L prefix of carr
#define OFF_SYR   2009376   // B*L row partial sums for std
#define OFF_SY2R  2015776   // B*L
#define OFF_ZC    2022176   // B*L*D cumsum of z
// end: 2431776 floats ~ 9.7 MB

__device__ __forceinline__ float wsum(float x){
#pragma unroll
  for (int o = 32; o > 0; o >>= 1) x += __shfl_xor(x, o, 64);
  return x;
}
__device__ __forceinline__ float eluf(float x){ return x > 0.f ? x : expm1f(x); }

// K0: transpose Wq,Wk,Wv [64,256] -> [256,64]
__global__ __launch_bounds__(256) void k_transpose(const float* __restrict__ Wq,
    const float* __restrict__ Wk, const float* __restrict__ Wv, float* __restrict__ wt){
  int idx = blockIdx.x*256 + threadIdx.x;
  if (idx >= 3*16384) return;
  int m = idx >> 14, r = idx & 16383, i = r >> 6, d = r & 63;
  const float* W = (m==0) ? Wq : ((m==1) ? Wk : Wv);
  wt[m*16384 + i*64 + d] = W[d*256 + i];
}

// K1: q,z,v GEMMs + per-row stats. 16 rows/block, 256 thr (wave g owns rows g+4j)
__global__ __launch_bounds__(256) void k_qzv(const float* __restrict__ x, const float* __restrict__ Wt,
    const float* __restrict__ bq, const float* __restrict__ bk, const float* __restrict__ bv,
    float* __restrict__ q, float* __restrict__ nq, float* __restrict__ z, float* __restrict__ v,
    float* __restrict__ sz, float* __restrict__ sv, float* __restrict__ snq){
  __shared__ float xs[16*256];
  int row0 = blockIdx.x * 16;
  int tid = threadIdx.x, d = tid & 63, g = tid >> 6;
  for (int k = tid; k < 4096; k += 256) xs[k] = x[row0*256 + k];
  __syncthreads();
  const float* Wtq = Wt;
  const float* Wtk = Wt + 16384;
  const float* Wtv = Wt + 32768;
  float aq[4] = {0,0,0,0}, ak[4] = {0,0,0,0}, av[4] = {0,0,0,0};
  for (int i = 0; i < 256; i++){
    float wq = Wtq[i*64+d], wk = Wtk[i*64+d], wv = Wtv[i*64+d];
#pragma unroll
    for (int j = 0; j < 4; j++){
      float xv = xs[(g+4*j)*256 + i];
      aq[j] = fmaf(xv, wq, aq[j]);
      ak[j] = fmaf(xv, wk, ak[j]);
      av[j] = fmaf(xv, wv, av[j]);
    }
  }
  float bqd = bq[d], bkd = bk[d], bvd = bv[d];
#pragma unroll
  for (int j = 0; j < 4; j++){
    int r = row0 + g + 4*j;
    float qv = eluf(aq[j] + bqd);
    float zv = eluf(ak[j] + bkd);
    float vv = av[j] + bvd;
    float sq2 = wsum(qv*qv);
    float sq1 = wsum(qv);
    float szv = wsum(zv);
    float svv = wsum(vv);
    float inv = 1.f / (sqrtf(sq2) + 1e-8f);
    q[r*64+d] = qv; nq[r*64+d] = qv*inv; z[r*64+d] = zv; v[r*64+d] = vv;
    if (d == 0){ sz[r] = szv; sv[r] = svv; snq[r] = sq1*inv; }
  }
}

// K2: prompts P,S + user state -> PzL, PsL, mps2, pNAM(masked). 1 block per b.
__global__ __launch_bounds__(256) void k_prompt(const float* __restrict__ P, const float* __restrict__ Sp,
    const int* __restrict__ uid, const float* __restrict__ prev_z, const float* __restrict__ prev_s,
    const float* __restrict__ Wt, const float* __restrict__ bk, const float* __restrict__ bv,
    float* __restrict__ PzL, float* __restrict__ PsL, float* __restrict__ mps2, float* __restrict__ pNAM){
  int b = blockIdx.x, tid = threadIdx.x;
  __shared__ float xP[2048], xS[2048];
  __shared__ float zP[512], vP[512], zS[512], vS[512];
  __shared__ float red[8];
  __shared__ float facs;
  for (int k = tid; k < 2048; k += 256){ xP[k] = P[b*2048 + k]; xS[k] = Sp[b*2048 + k]; }
  __syncthreads();
  const float* Wtk = Wt + 16384;
  const float* Wtv = Wt + 32768;
  for (int idx = tid; idx < 512; idx += 256){
    int t = idx >> 6, d = idx & 63;
    float aPk=0,aPv=0,aSk=0,aSv=0;
    for (int i = 0; i < 256; i++){
      float wk = Wtk[i*64+d], wv = Wtv[i*64+d];
      float xp = xP[t*256+i], xq = xS[t*256+i];
      aPk = fmaf(xp,wk,aPk); aPv = fmaf(xp,wv,aPv);
      aSk = fmaf(xq,wk,aSk); aSv = fmaf(xq,wv,aSv);
    }
    zP[idx] = eluf(aPk + bk[d]); vP[idx] = aPv + bv[d];
    zS[idx] = eluf(aSk + bk[d]); vS[idx] = aSv + bv[d];
  }
  __syncthreads();
  float spv[16], ssv[16];
  float l1=0.f, l2=0.f, l3=0.f, l4=0.f;
  int p = tid >> 2, q0 = (tid & 3) * 16;
#pragma unroll
  for (int k = 0; k < 16; k++){
    int qq = q0 + k;
    float sp = 0.f, ss = 0.f;
#pragma unroll
    for (int t = 0; t < 8; t++){
      sp = fmaf(zP[t*64+p], vP[t*64+qq], sp);
      ss = fmaf(zS[t*64+p], vS[t*64+qq], ss);
    }
    spv[k] = sp; ssv[k] = ss;
    l1 += sp; l2 += sp*sp; l3 += ss; l4 += ss*ss;
  }
  float sums[4] = {l1,l2,l3,l4};
  float tot[4];
  for (int r = 0; r < 4; r++){
    float val = wsum(sums[r]);
    if ((tid & 63) == 0) red[tid >> 6] = val;
    __syncthreads();
    tot[r] = red[0] + red[1] + red[2] + red[3];
    __syncthreads();
  }
  float mP = tot[0] * (1.f/4096.f);
  float varP = tot[1] * (1.f/4096.f) - mP*mP;
  float invP = rsqrtf(varP + 1e-5f);
  float mS = tot[2] * (1.f/4096.f);
  float varS = tot[3] * (1.f/4096.f) - mS*mS;
  float invS = rsqrtf(varS + 1e-5f);
  if (tid == 0) mps2[b] = varP * invP * invP;  // E[PsL^2]
  int u = uid[b];
  if (tid < 64){
    int d = tid;
    float zc = 0.f, zs = 0.f;
#pragma unroll
    for (int t = 0; t < 8; t++){ zc += zP[t*64+d]; zs += zS[t*64+d]; }
    float s1 = wsum(zc), s2 = wsum(zc*zc);
    float mz = s1*(1.f/64.f), vz = s2*(1.f/64.f) - mz*mz;
    PzL[b*64+d] = (zc - mz) * rsqrtf(vz + 1e-5f);
    float t1 = wsum(zs), t2 = wsum(zs*zs);
    float mzs = t1*(1.f/64.f), vzs = t2*(1.f/64.f) - mzs*mzs;
    float szl = (zs - mzs) * rsqrtf(vzs + 1e-5f);
    float pzv = prev_z[u*64 + d];
    float zu = pzv + szl;
    float zl2 = wsum(zu*zu);
    float psumv = wsum(pzv);
    float fac = ((psumv != 0.f) ? 1.f : 0.f) / (sqrtf(zl2) + 1e-8f);
    if (d == 0) facs = fac;
  }
  __syncthreads();
  float fac = facs;
  const float* psrow = prev_s + (size_t)u * 4096;
#pragma unroll
  for (int k = 0; k < 16; k++){
    int o = p*64 + q0 + k;
    float psl = (spv[k] - mP) * invP;
    PsL[b*4096 + o] = psl;
    float su = psrow[o] + (ssv[k] - mS) * invS;
    pNAM[b*4096 + o] = su * fac;
  }
}

// K3a: per (b,l): colsum_l = sum_{t<=l}(z_t.z_l)(v_t.v_l), h_l = diag term, c_l = z_l^T PsL v_l
__global__ __launch_bounds__(256) void k_gram(const float* __restrict__ z, const float* __restrict__ v,
    const float* __restrict__ PsL, float* __restrict__ colsum, float* __restrict__ harr, float* __restrict__ carr){
  int b = blockIdx.x / 7, lt = blockIdx.x % 7;
  int l0 = lt * 32;
  int tid = threadIdx.x, lane = tid & 63, g = tid >> 6;
  __shared__ __align__(16) float zl[32*64];
  __shared__ __align__(16) float vl[32*64];
  const float* zb = z + b * (L_*D_);
  const float* vb = v + b * (L_*D_);
  for (int k = tid; k < 2048; k += 256){
    int l = l0 + (k >> 6);
    zl[k] = (l < L_) ? zb[l*64 + (k & 63)] : 0.f;
    vl[k] = (l < L_) ? vb[l*64 + (k & 63)] : 0.f;
  }
  __syncthreads();
  for (int j = 0; j < 8; j++){
    int li = g + 4*j;
    int l = l0 + li;
    if (l >= L_) continue;
    // c_l
    float wacc = 0.f;
    const float* psr = PsL + b*4096 + lane*64;
#pragma unroll
    for (int qq = 0; qq < 64; qq += 4){
      float4 p4 = *(const float4*)(psr + qq);
      float4 v4 = *(const float4*)(&vl[li*64 + qq]);
      wacc += p4.x*v4.x + p4.y*v4.y + p4.z*v4.z + p4.w*v4.w;
    }
    float c = wsum(zl[li*64 + lane] * wacc);
    // colsum + h
    float ps_acc = 0.f, hval = 0.f;
    for (int tbase = 0; tbase <= l; tbase += 64){
      int t = tbase + lane;
      float pz = 0.f, pv = 0.f;
      if (t <= l){
        const float* zr = zb + t*64;
        const float* vr = vb + t*64;
#pragma unroll
        for (int dd = 0; dd < 64; dd += 4){
          float4 za = *(const float4*)(zr + dd);
          float4 zc4 = *(const float4*)(&zl[li*64 + dd]);
          pz += za.x*zc4.x + za.y*zc4.y + za.z*zc4.z + za.w*zc4.w;
          float4 va = *(const float4*)(vr + dd);
          float4 vc4 = *(const float4*)(&vl[li*64 + dd]);
          pv += va.x*vc4.x + va.y*vc4.y + va.z*vc4.z + va.w*vc4.w;
        }
      }
      float prod = pz * pv;
      ps_acc += prod;
      if ((l & ~63) == tbase) hval = __shfl(prod, l & 63, 64);
    }
    float cs = wsum(ps_acc);
    if (lane == 0){
      colsum[b*L_ + l] = cs;
      harr[b*L_ + l]  = hval;
      carr[b*L_ + l]  = c;
    }
  }
}

// K3b: per-b prefix sums: Zcum (per-lane independent) + 3 scalar scans (shfl-based)
__global__ __launch_bounds__(64) void k_cumsum(const float* __restrict__ z,
    const float* __restrict__ sz, const float* __restrict__ sv,
    const float* __restrict__ colsum, const float* __restrict__ harr, const float* __restrict__ carr,
    float* __restrict__ Zcum, float* __restrict__ cM, float* __restrict__ cR, float* __restrict__ cC){
  int b = blockIdx.x, lane = threadIdx.x;
  const float* zb = z + b*12800;
  float* Zb = Zcum + b*12800;
  float Zc = 0.f;
  for (int l = 0; l < 200; l += 4){
    float a0 = zb[(l+0)*64+lane];
    float a1 = zb[(l+1)*64+lane];
    float a2 = zb[(l+2)*64+lane];
    float a3 = zb[(l+3)*64+lane];
    Zc += a0; Zb[(l+0)*64+lane] = Zc;
    Zc += a1; Zb[(l+1)*64+lane] = Zc;
    Zc += a2; Zb[(l+2)*64+lane] = Zc;
    Zc += a3; Zb[(l+3)*64+lane] = Zc;
  }
  float carryM = 0.f, carryR = 0.f, carryC = 0.f;
#pragma unroll
  for (int c = 0; c < 4; c++){
    int l = c*64 + lane;
    bool valid = l < 200;
    int row = b*200 + l;
    float tm = valid ? sz[row]*sv[row] : 0.f;
    float tr = valid ? 2.f*colsum[row] - harr[row] : 0.f;
    float tc = valid ? carr[row] : 0.f;
#pragma unroll
    for (int o = 1; o < 64; o <<= 1){
      float y0 = __shfl_up(tm, o, 64);
      float y1 = __shfl_up(tr, o, 64);
      float y2 = __shfl_up(tc, o, 64);
      if (lane >= o){ tm += y0; tr += y1; tc += y2; }
    }
    tm += carryM; tr += carryR; tc += carryC;
    if (valid){ cM[row] = tm; cR[row] = tr; cC[row] = tc; }
    carryM = __shfl(tm, 63, 64);
    carryR = __shfl(tr, 63, 64);
    carryC = __shfl(tc, 63, 64);
  }
}

// K4: per (b,l): coefficients (from prefix arrays) + causal linear attention + final LN + std partials
__global__ __launch_bounds__(64) void k_final(const float* __restrict__ nq, const float* __restrict__ z,
    const float* __restrict__ v, const float* __restrict__ q, const float* __restrict__ Zcum,
    const float* __restrict__ PzL, const float* __restrict__ mps2, const float* __restrict__ snq,
    const float* __restrict__ cM, const float* __restrict__ cR, const float* __restrict__ cC,
    const float* __restrict__ PsL, const float* __restrict__ pNAM,
    float* __restrict__ out, float* __restrict__ Syr, float* __restrict__ Sy2r){
  int row = blockIdx.x;
  int b = row / 200, l = row % 200;
  int lane = threadIdx.x;
  __shared__ __align__(16) float nqs[64];
  __shared__ float sc[64];
  nqs[lane] = nq[row*64 + lane];
  // ---- coefficients ----
  float zc = Zcum[row*64 + lane];
  float s1 = wsum(zc), s2 = wsum(zc*zc);
  float mz = s1*(1.f/64.f), vz = s2*(1.f/64.f) - mz*mz;
  float zf = (zc - mz) * rsqrtf(vz + 1e-5f) + PzL[b*64 + lane];
  float zl2 = wsum(zf*zf);
  float a = sqrtf(zl2) + 1e-8f;
  float m = cM[row] * (1.f/4096.f);
  float var = cR[row] * (1.f/4096.f) - m*m;
  float inv = rsqrtf(var + 1e-5f);
  float varT = inv*inv*var + 2.f*inv*cC[row]*(1.f/4096.f) + mps2[b];
  float invT = rsqrtf(varT + 1e-5f*a*a);
  float cAv = invT*inv;
  float cBv = invT*inv*m*snq[row];
  float cCv = invT;
  // std partials
  float y = q[row*64 + lane] / fmaxf(zf, 1e-6f);
  float ys = wsum(y), ys2 = wsum(y*y);
  if (lane == 0){ Syr[row] = ys; Sy2r[row] = ys2; }
  __syncthreads();
  // ---- attention core ----
  const float* zb = z + b*12800;
  const float* vb = v + b*12800;
  float acc = 0.f;
  for (int tbase = 0; tbase <= l; tbase += 64){
    int t = tbase + lane;
    float s = 0.f;
    if (t <= l){
      const float* zr = zb + t*64;
#pragma unroll
      for (int dd = 0; dd < 64; dd += 4){
        float4 za = *(const float4*)(zr + dd);
        s += nqs[dd]*za.x + nqs[dd+1]*za.y + nqs[dd+2]*za.z + nqs[dd+3]*za.w;
      }
    }
    __syncthreads();
    sc[lane] = s;
    __syncthreads();
    int tmax = min(63, l - tbase);
    for (int tt = 0; tt <= tmax; tt++)
      acc = fmaf(sc[tt], vb[(tbase+tt)*64 + lane], acc);
  }
  float t1 = 0.f, t2 = 0.f;
  const float* ps = PsL + b*4096;
  const float* pn = pNAM + b*4096;
  for (int p = 0; p < 64; p++){
    float np = nqs[p];
    t1 = fmaf(np, ps[p*64 + lane], t1);
    t2 = fmaf(np, pn[p*64 + lane], t2);
  }
  float NA1 = cAv*acc - cBv + cCv*t1 + t2;
  float r1 = wsum(NA1), r2 = wsum(NA1*NA1);
  float mm = r1*(1.f/64.f), vv = r2*(1.f/64.f) - mm*mm;
  out[row*64 + lane] = (NA1 - mm) * rsqrtf(vv + 1e-5f);
}

// K5: finalize std (ddof=1) over all B*L*D elements; reduce 6400 row partials
__global__ __launch_bounds__(256) void k_std(const float* __restrict__ Syr, const float* __restrict__ Sy2r,
    float* __restrict__ out){
  __shared__ float redA[4], redB[4];
  int tid = threadIdx.x, lane = tid & 63, g = tid >> 6;
  float a = 0.f, b2 = 0.f;
  for (int i = tid; i < 6400; i += 256){ a += Syr[i]; b2 += Sy2r[i]; }
  a = wsum(a); b2 = wsum(b2);
  if (lane == 0){ redA[g] = a; redB[g] = b2; }
  __syncthreads();
  if (tid == 0){
    float A = redA[0]+redA[1]+redA[2]+redA[3];
    float B2 = redB[0]+redB[1]+redB[2]+redB[3];
    const float N = 409600.f;
    float var = (B2 - A*A/N) / (N - 1.f);
    out[409600] = sqrtf(fmaxf(var, 0.f));
  }
}

extern "C" void kernel_launch(void* const* d_in, const int* in_sizes, int n_in,
                              void* d_out, int out_size, void* d_ws, size_t ws_size,
                              hipStream_t stream) {
  const int*   uid    = (const int*)d_in[0];
  const float* seqs   = (const float*)d_in[1];
  const float* P      = (const float*)d_in[2];
  const float* S      = (const float*)d_in[3];
  const float* prev_z = (const float*)d_in[4];
  const float* prev_s = (const float*)d_in[5];
  const float* Wq     = (const float*)d_in[6];
  const float* bq     = (const float*)d_in[7];
  const float* Wk     = (const float*)d_in[8];
  const float* bk     = (const float*)d_in[9];
  const float* Wv     = (const float*)d_in[10];
  const float* bv     = (const float*)d_in[11];
  float* w   = (float*)d_ws;
  float* out = (float*)d_out;

  k_transpose<<<192, 256, 0, stream>>>(Wq, Wk, Wv, w + OFF_WT);
  k_qzv<<<400, 256, 0, stream>>>(seqs, w + OFF_WT, bq, bk, bv,
      w + OFF_Q, w + OFF_NQ, w + OFF_Z, w + OFF_V, w + OFF_SZ, w + OFF_SV, w + OFF_SNQ);
  k_prompt<<<32, 256, 0, stream>>>(P, S, uid, prev_z, prev_s, w + OFF_WT, bk, bv,
      w + OFF_PZL, w + OFF_PSL, w + OFF_MPS2, w + OFF_PNAM);
  k_gram<<<224, 256, 0, stream>>>(w + OFF_Z, w + OFF_V, w + OFF_PSL,
      w + OFF_COL, w + OFF_H, w + OFF_C);
  k_cumsum<<<32, 64, 0, stream>>>(w + OFF_Z, w + OFF_SZ, w + OFF_SV,
      w + OFF_COL, w + OFF_H, w + OFF_C,
      w + OFF_ZC, w + OFF_CM, w + OFF_CR, w + OFF_CCP);
  k_final<<<6400, 64, 0, stream>>>(w + OFF_NQ, w + OFF_Z, w + OFF_V, w + OFF_Q, w + OFF_ZC,
      w + OFF_PZL, w + OFF_MPS2, w + OFF_SNQ,
      w + OFF_CM, w + OFF_CR, w + OFF_CCP,
      w + OFF_PSL, w + OFF_PNAM,
      out, w + OFF_SYR, w + OFF_SY2R);
  k_std<<<1, 256, 0, stream>>>(w + OFF_SYR, w + OFF_SY2R, out);
}

// Round 3
// 152.412 us; speedup vs baseline: 2.6714x; 1.4054x over previous
//
#include <hip/hip_runtime.h>
#include <math.h>

// Problem constants
#define B_   32
#define L_   200
#define DIN_ 256
#define D_   64
#define PL_  8

// ws layout (float offsets)
#define OFF_WT    0         // 3*16384 transposed weights [i][d]
#define OFF_Q     49152     // B*L*D
#define OFF_NQ    458752
#define OFF_Z     868352
#define OFF_V     1277952
#define OFF_SZ    1687552   // B*L
#define OFF_SV    1693952
#define OFF_SNQ   1700352
#define OFF_PZL   1706752   // B*D
#define OFF_PSL   1708800   // B*D*D
#define OFF_PNAM  1839872   // B*D*D
#define OFF_MPS2  1970944   // B
#define OFF_COL   1970976   // B*L
#define OFF_H     1977376
#define OFF_C     1983776
#define OFF_CM    1990176   // B*L prefix of sz*sv
#define OFF_CR    1996576   // B*L prefix of 2*col-h
#define OFF_CCP   2002976   // B*L prefix of carr
#define OFF_SYR   2009376   // B*L row partial sums for std
#define OFF_SY2R  2015776   // B*L
#define OFF_ZC    2022176   // B*L*D cumsum of z
#define OFF_CP    2431776   // B*L*8 colsum partials per t-tile
// end: 2482976 floats ~ 9.93 MB

__device__ __forceinline__ float wsum(float x){
#pragma unroll
  for (int o = 32; o > 0; o >>= 1) x += __shfl_xor(x, o, 64);
  return x;
}
__device__ __forceinline__ float eluf(float x){ return x > 0.f ? x : expm1f(x); }

// K0: transpose Wq,Wk,Wv [64,256] -> [256,64]
__global__ __launch_bounds__(256) void k_transpose(const float* __restrict__ Wq,
    const float* __restrict__ Wk, const float* __restrict__ Wv, float* __restrict__ wt){
  int idx = blockIdx.x*256 + threadIdx.x;
  if (idx >= 3*16384) return;
  int m = idx >> 14, r = idx & 16383, i = r >> 6, d = r & 63;
  const float* W = (m==0) ? Wq : ((m==1) ? Wk : Wv);
  wt[m*16384 + i*64 + d] = W[d*256 + i];
}

// K1: q,z,v GEMMs + per-row stats. 16 rows/block, 256 thr (wave g owns rows g+4j)
__global__ __launch_bounds__(256) void k_qzv(const float* __restrict__ x, const float* __restrict__ Wt,
    const float* __restrict__ bq, const float* __restrict__ bk, const float* __restrict__ bv,
    float* __restrict__ q, float* __restrict__ nq, float* __restrict__ z, float* __restrict__ v,
    float* __restrict__ sz, float* __restrict__ sv, float* __restrict__ snq){
  __shared__ float xs[16*256];
  int row0 = blockIdx.x * 16;
  int tid = threadIdx.x, d = tid & 63, g = tid >> 6;
  for (int k = tid; k < 4096; k += 256) xs[k] = x[row0*256 + k];
  __syncthreads();
  const float* Wtq = Wt;
  const float* Wtk = Wt + 16384;
  const float* Wtv = Wt + 32768;
  float aq[4] = {0,0,0,0}, ak[4] = {0,0,0,0}, av[4] = {0,0,0,0};
  for (int i = 0; i < 256; i++){
    float wq = Wtq[i*64+d], wk = Wtk[i*64+d], wv = Wtv[i*64+d];
#pragma unroll
    for (int j = 0; j < 4; j++){
      float xv = xs[(g+4*j)*256 + i];
      aq[j] = fmaf(xv, wq, aq[j]);
      ak[j] = fmaf(xv, wk, ak[j]);
      av[j] = fmaf(xv, wv, av[j]);
    }
  }
  float bqd = bq[d], bkd = bk[d], bvd = bv[d];
#pragma unroll
  for (int j = 0; j < 4; j++){
    int r = row0 + g + 4*j;
    float qv = eluf(aq[j] + bqd);
    float zv = eluf(ak[j] + bkd);
    float vv = av[j] + bvd;
    float sq2 = wsum(qv*qv);
    float sq1 = wsum(qv);
    float szv = wsum(zv);
    float svv = wsum(vv);
    float inv = 1.f / (sqrtf(sq2) + 1e-8f);
    q[r*64+d] = qv; nq[r*64+d] = qv*inv; z[r*64+d] = zv; v[r*64+d] = vv;
    if (d == 0){ sz[r] = szv; sv[r] = svv; snq[r] = sq1*inv; }
  }
}

// K2: prompts P,S + user state -> PzL, PsL, mps2, pNAM(masked). 1 block per b.
__global__ __launch_bounds__(256) void k_prompt(const float* __restrict__ P, const float* __restrict__ Sp,
    const int* __restrict__ uid, const float* __restrict__ prev_z, const float* __restrict__ prev_s,
    const float* __restrict__ Wt, const float* __restrict__ bk, const float* __restrict__ bv,
    float* __restrict__ PzL, float* __restrict__ PsL, float* __restrict__ mps2, float* __restrict__ pNAM){
  int b = blockIdx.x, tid = threadIdx.x;
  __shared__ float xP[2048], xS[2048];
  __shared__ float zP[512], vP[512], zS[512], vS[512];
  __shared__ float red[8];
  __shared__ float facs;
  for (int k = tid; k < 2048; k += 256){ xP[k] = P[b*2048 + k]; xS[k] = Sp[b*2048 + k]; }
  __syncthreads();
  const float* Wtk = Wt + 16384;
  const float* Wtv = Wt + 32768;
  for (int idx = tid; idx < 512; idx += 256){
    int t = idx >> 6, d = idx & 63;
    float aPk=0,aPv=0,aSk=0,aSv=0;
    for (int i = 0; i < 256; i++){
      float wk = Wtk[i*64+d], wv = Wtv[i*64+d];
      float xp = xP[t*256+i], xq = xS[t*256+i];
      aPk = fmaf(xp,wk,aPk); aPv = fmaf(xp,wv,aPv);
      aSk = fmaf(xq,wk,aSk); aSv = fmaf(xq,wv,aSv);
    }
    zP[idx] = eluf(aPk + bk[d]); vP[idx] = aPv + bv[d];
    zS[idx] = eluf(aSk + bk[d]); vS[idx] = aSv + bv[d];
  }
  __syncthreads();
  float spv[16], ssv[16];
  float l1=0.f, l2=0.f, l3=0.f, l4=0.f;
  int p = tid >> 2, q0 = (tid & 3) * 16;
#pragma unroll
  for (int k = 0; k < 16; k++){
    int qq = q0 + k;
    float sp = 0.f, ss = 0.f;
#pragma unroll
    for (int t = 0; t < 8; t++){
      sp = fmaf(zP[t*64+p], vP[t*64+qq], sp);
      ss = fmaf(zS[t*64+p], vS[t*64+qq], ss);
    }
    spv[k] = sp; ssv[k] = ss;
    l1 += sp; l2 += sp*sp; l3 += ss; l4 += ss*ss;
  }
  float sums[4] = {l1,l2,l3,l4};
  float tot[4];
  for (int r = 0; r < 4; r++){
    float val = wsum(sums[r]);
    if ((tid & 63) == 0) red[tid >> 6] = val;
    __syncthreads();
    tot[r] = red[0] + red[1] + red[2] + red[3];
    __syncthreads();
  }
  float mP = tot[0] * (1.f/4096.f);
  float varP = tot[1] * (1.f/4096.f) - mP*mP;
  float invP = rsqrtf(varP + 1e-5f);
  float mS = tot[2] * (1.f/4096.f);
  float varS = tot[3] * (1.f/4096.f) - mS*mS;
  float invS = rsqrtf(varS + 1e-5f);
  if (tid == 0) mps2[b] = varP * invP * invP;  // E[PsL^2]
  int u = uid[b];
  if (tid < 64){
    int d = tid;
    float zc = 0.f, zs = 0.f;
#pragma unroll
    for (int t = 0; t < 8; t++){ zc += zP[t*64+d]; zs += zS[t*64+d]; }
    float s1 = wsum(zc), s2 = wsum(zc*zc);
    float mz = s1*(1.f/64.f), vz = s2*(1.f/64.f) - mz*mz;
    PzL[b*64+d] = (zc - mz) * rsqrtf(vz + 1e-5f);
    float t1 = wsum(zs), t2 = wsum(zs*zs);
    float mzs = t1*(1.f/64.f), vzs = t2*(1.f/64.f) - mzs*mzs;
    float szl = (zs - mzs) * rsqrtf(vzs + 1e-5f);
    float pzv = prev_z[u*64 + d];
    float zu = pzv + szl;
    float zl2 = wsum(zu*zu);
    float psumv = wsum(pzv);
    float fac = ((psumv != 0.f) ? 1.f : 0.f) / (sqrtf(zl2) + 1e-8f);
    if (d == 0) facs = fac;
  }
  __syncthreads();
  float fac = facs;
  const float* psrow = prev_s + (size_t)u * 4096;
#pragma unroll
  for (int k = 0; k < 16; k++){
    int o = p*64 + q0 + k;
    float psl = (spv[k] - mP) * invP;
    PsL[b*4096 + o] = psl;
    float su = psrow[o] + (ssv[k] - mS) * invS;
    pNAM[b*4096 + o] = su * fac;
  }
}

// K3a: tiled Gram: for tile-pair (lt,tt<=lt) compute partial colsums + diag h
#define PADK 68
__global__ __launch_bounds__(256) void k_gram_tile(const float* __restrict__ z, const float* __restrict__ v,
    float* __restrict__ colpart, float* __restrict__ harr){
  int b = blockIdx.x / 28, pi = blockIdx.x % 28;
  int lt = 0;
  while ((lt+1)*(lt+2)/2 <= pi) lt++;
  int tt = pi - lt*(lt+1)/2;
  int tid = threadIdx.x;
  __shared__ __align__(16) float zl[32*PADK];
  __shared__ __align__(16) float vl[32*PADK];
  __shared__ __align__(16) float zt[32*PADK];
  __shared__ __align__(16) float vt[32*PADK];
  __shared__ float ps[8*32];
  const float* zb = z + b*12800;
  const float* vb = v + b*12800;
  int l0 = lt*32, t0 = tt*32;
  for (int k = tid; k < 2048; k += 256){
    int r = k >> 6, d = k & 63;
    int lr = l0 + r, tr = t0 + r;
    zl[r*PADK+d] = (lr < L_) ? zb[lr*64+d] : 0.f;
    vl[r*PADK+d] = (lr < L_) ? vb[lr*64+d] : 0.f;
    zt[r*PADK+d] = (tr < L_) ? zb[tr*64+d] : 0.f;
    vt[r*PADK+d] = (tr < L_) ? vb[tr*64+d] : 0.f;
  }
  __syncthreads();
  int r = tid & 31, c4 = tid >> 5;   // 32 rows x 8 col-groups
  int c0 = c4 * 4;
  float az[4] = {0,0,0,0}, av[4] = {0,0,0,0};
  for (int k = 0; k < 64; k += 4){
    float4 zr = *(const float4*)&zl[r*PADK+k];
    float4 vr = *(const float4*)&vl[r*PADK+k];
#pragma unroll
    for (int j = 0; j < 4; j++){
      float4 zc = *(const float4*)&zt[(c0+j)*PADK+k];
      az[j] += zr.x*zc.x + zr.y*zc.y + zr.z*zc.z + zr.w*zc.w;
      float4 vc = *(const float4*)&vt[(c0+j)*PADK+k];
      av[j] += vr.x*vc.x + vr.y*vc.y + vr.z*vc.z + vr.w*vc.w;
    }
  }
  int l = l0 + r;
  bool diag = (lt == tt);
  float part = 0.f;
#pragma unroll
  for (int j = 0; j < 4; j++){
    int c = c0 + j;
    float hv = az[j] * av[j];
    if (!diag || c <= r) part += hv;
    if (diag && c == r && l < L_) harr[b*L_ + l] = hv;
  }
  ps[c4*32 + r] = part;
  __syncthreads();
  if (tid < 32){
    float s = 0.f;
#pragma unroll
    for (int c4i = 0; c4i < 8; c4i++) s += ps[c4i*32 + tid];
    int ll = l0 + tid;
    if (ll < L_) colpart[(b*L_ + ll)*8 + tt] = s;
  }
}

// K3b: per (b,l): reduce colsum partials + c_l = z_l^T PsL v_l
__global__ __launch_bounds__(64) void k_redc(const float* __restrict__ z, const float* __restrict__ v,
    const float* __restrict__ PsL, const float* __restrict__ colpart,
    float* __restrict__ colsum, float* __restrict__ carr){
  int row = blockIdx.x;
  int b = row / L_, l = row % L_;
  int lane = threadIdx.x;
  __shared__ __align__(16) float vls[64];
  float zv = z[row*64 + lane];
  vls[lane] = v[row*64 + lane];
  __syncthreads();
  const float* psr = PsL + b*4096 + lane*64;
  float wacc = 0.f;
#pragma unroll
  for (int qq = 0; qq < 64; qq += 4){
    float4 p4 = *(const float4*)(psr + qq);
    float4 v4 = *(const float4*)(&vls[qq]);
    wacc += p4.x*v4.x + p4.y*v4.y + p4.z*v4.z + p4.w*v4.w;
  }
  float c = wsum(zv * wacc);
  int lt = l >> 5;
  float cp = (lane <= lt) ? colpart[row*8 + lane] : 0.f;
  float cs = wsum(cp);
  if (lane == 0){ colsum[row] = cs; carr[row] = c; }
}

// K3c: per-b prefix sums: Zcum (per-lane independent) + 3 scalar scans (shfl-based)
__global__ __launch_bounds__(64) void k_cumsum(const float* __restrict__ z,
    const float* __restrict__ sz, const float* __restrict__ sv,
    const float* __restrict__ colsum, const float* __restrict__ harr, const float* __restrict__ carr,
    float* __restrict__ Zcum, float* __restrict__ cM, float* __restrict__ cR, float* __restrict__ cC){
  int b = blockIdx.x, lane = threadIdx.x;
  const float* zb = z + b*12800;
  float* Zb = Zcum + b*12800;
  float Zc = 0.f;
  for (int l = 0; l < 200; l += 4){
    float a0 = zb[(l+0)*64+lane];
    float a1 = zb[(l+1)*64+lane];
    float a2 = zb[(l+2)*64+lane];
    float a3 = zb[(l+3)*64+lane];
    Zc += a0; Zb[(l+0)*64+lane] = Zc;
    Zc += a1; Zb[(l+1)*64+lane] = Zc;
    Zc += a2; Zb[(l+2)*64+lane] = Zc;
    Zc += a3; Zb[(l+3)*64+lane] = Zc;
  }
  float carryM = 0.f, carryR = 0.f, carryC = 0.f;
#pragma unroll
  for (int c = 0; c < 4; c++){
    int l = c*64 + lane;
    bool valid = l < 200;
    int row = b*200 + l;
    float tm = valid ? sz[row]*sv[row] : 0.f;
    float tr = valid ? 2.f*colsum[row] - harr[row] : 0.f;
    float tc = valid ? carr[row] : 0.f;
#pragma unroll
    for (int o = 1; o < 64; o <<= 1){
      float y0 = __shfl_up(tm, o, 64);
      float y1 = __shfl_up(tr, o, 64);
      float y2 = __shfl_up(tc, o, 64);
      if (lane >= o){ tm += y0; tr += y1; tc += y2; }
    }
    tm += carryM; tr += carryR; tc += carryC;
    if (valid){ cM[row] = tm; cR[row] = tr; cC[row] = tc; }
    carryM = __shfl(tm, 63, 64);
    carryR = __shfl(tr, 63, 64);
    carryC = __shfl(tc, 63, 64);
  }
}

// K4: per (b,l): coefficients + causal linear attention + final LN + std partials
__global__ __launch_bounds__(64) void k_final(const float* __restrict__ nq, const float* __restrict__ z,
    const float* __restrict__ v, const float* __restrict__ q, const float* __restrict__ Zcum,
    const float* __restrict__ PzL, const float* __restrict__ mps2, const float* __restrict__ snq,
    const float* __restrict__ cM, const float* __restrict__ cR, const float* __restrict__ cC,
    const float* __restrict__ PsL, const float* __restrict__ pNAM,
    float* __restrict__ out, float* __restrict__ Syr, float* __restrict__ Sy2r){
  int row = blockIdx.x;
  int b = row / 200, l = row % 200;
  int lane = threadIdx.x;
  __shared__ __align__(16) float nqs[64];
  __shared__ float sc[64];
  nqs[lane] = nq[row*64 + lane];
  // ---- coefficients ----
  float zc = Zcum[row*64 + lane];
  float s1 = wsum(zc), s2 = wsum(zc*zc);
  float mz = s1*(1.f/64.f), vz = s2*(1.f/64.f) - mz*mz;
  float zf = (zc - mz) * rsqrtf(vz + 1e-5f) + PzL[b*64 + lane];
  float zl2 = wsum(zf*zf);
  float a = sqrtf(zl2) + 1e-8f;
  float m = cM[row] * (1.f/4096.f);
  float var = cR[row] * (1.f/4096.f) - m*m;
  float inv = rsqrtf(var + 1e-5f);
  float varT = inv*inv*var + 2.f*inv*cC[row]*(1.f/4096.f) + mps2[b];
  float invT = rsqrtf(varT + 1e-5f*a*a);
  float cAv = invT*inv;
  float cBv = invT*inv*m*snq[row];
  float cCv = invT;
  // std partials
  float y = q[row*64 + lane] / fmaxf(zf, 1e-6f);
  float ys = wsum(y), ys2 = wsum(y*y);
  if (lane == 0){ Syr[row] = ys; Sy2r[row] = ys2; }
  __syncthreads();
  // ---- attention core ----
  const float* zb = z + b*12800;
  const float* vb = v + b*12800;
  float a0 = 0.f, a1 = 0.f, a2 = 0.f, a3 = 0.f;
  for (int tbase = 0; tbase <= l; tbase += 64){
    int t = tbase + lane;
    float s = 0.f;
    if (t <= l){
      const float* zr = zb + t*64;
#pragma unroll
      for (int dd = 0; dd < 64; dd += 4){
        float4 za = *(const float4*)(zr + dd);
        s += nqs[dd]*za.x + nqs[dd+1]*za.y + nqs[dd+2]*za.z + nqs[dd+3]*za.w;
      }
    }
    __syncthreads();
    sc[lane] = s;
    __syncthreads();
    int tmax = min(63, l - tbase);
    const float* vrb = vb + tbase*64 + lane;
    int tt = 0;
    for (; tt + 3 <= tmax; tt += 4){
      a0 = fmaf(sc[tt],   vrb[tt*64],       a0);
      a1 = fmaf(sc[tt+1], vrb[tt*64 + 64],  a1);
      a2 = fmaf(sc[tt+2], vrb[tt*64 + 128], a2);
      a3 = fmaf(sc[tt+3], vrb[tt*64 + 192], a3);
    }
    for (; tt <= tmax; tt++) a0 = fmaf(sc[tt], vrb[tt*64], a0);
  }
  float acc = (a0 + a1) + (a2 + a3);
  float t1 = 0.f, t2 = 0.f, t3 = 0.f, t4 = 0.f;
  const float* ps = PsL + b*4096;
  const float* pn = pNAM + b*4096;
  for (int p = 0; p < 64; p += 2){
    float np0 = nqs[p], np1 = nqs[p+1];
    t1 = fmaf(np0, ps[p*64 + lane], t1);
    t3 = fmaf(np1, ps[(p+1)*64 + lane], t3);
    t2 = fmaf(np0, pn[p*64 + lane], t2);
    t4 = fmaf(np1, pn[(p+1)*64 + lane], t4);
  }
  t1 += t3; t2 += t4;
  float NA1 = cAv*acc - cBv + cCv*t1 + t2;
  float r1 = wsum(NA1), r2 = wsum(NA1*NA1);
  float mm = r1*(1.f/64.f), vv = r2*(1.f/64.f) - mm*mm;
  out[row*64 + lane] = (NA1 - mm) * rsqrtf(vv + 1e-5f);
}

// K5: finalize std (ddof=1) over all B*L*D elements; reduce 6400 row partials
__global__ __launch_bounds__(256) void k_std(const float* __restrict__ Syr, const float* __restrict__ Sy2r,
    float* __restrict__ out){
  __shared__ float redA[4], redB[4];
  int tid = threadIdx.x, lane = tid & 63, g = tid >> 6;
  float a = 0.f, b2 = 0.f;
  for (int i = tid; i < 6400; i += 256){ a += Syr[i]; b2 += Sy2r[i]; }
  a = wsum(a); b2 = wsum(b2);
  if (lane == 0){ redA[g] = a; redB[g] = b2; }
  __syncthreads();
  if (tid == 0){
    float A = redA[0]+redA[1]+redA[2]+redA[3];
    float B2 = redB[0]+redB[1]+redB[2]+redB[3];
    const float N = 409600.f;
    float var = (B2 - A*A/N) / (N - 1.f);
    out[409600] = sqrtf(fmaxf(var, 0.f));
  }
}

extern "C" void kernel_launch(void* const* d_in, const int* in_sizes, int n_in,
                              void* d_out, int out_size, void* d_ws, size_t ws_size,
                              hipStream_t stream) {
  const int*   uid    = (const int*)d_in[0];
  const float* seqs   = (const float*)d_in[1];
  const float* P      = (const float*)d_in[2];
  const float* S      = (const float*)d_in[3];
  const float* prev_z = (const float*)d_in[4];
  const float* prev_s = (const float*)d_in[5];
  const float* Wq     = (const float*)d_in[6];
  const float* bq     = (const float*)d_in[7];
  const float* Wk     = (const float*)d_in[8];
  const float* bk     = (const float*)d_in[9];
  const float* Wv     = (const float*)d_in[10];
  const float* bv     = (const float*)d_in[11];
  float* w   = (float*)d_ws;
  float* out = (float*)d_out;

  k_transpose<<<192, 256, 0, stream>>>(Wq, Wk, Wv, w + OFF_WT);
  k_qzv<<<400, 256, 0, stream>>>(seqs, w + OFF_WT, bq, bk, bv,
      w + OFF_Q, w + OFF_NQ, w + OFF_Z, w + OFF_V, w + OFF_SZ, w + OFF_SV, w + OFF_SNQ);
  k_prompt<<<32, 256, 0, stream>>>(P, S, uid, prev_z, prev_s, w + OFF_WT, bk, bv,
      w + OFF_PZL, w + OFF_PSL, w + OFF_MPS2, w + OFF_PNAM);
  k_gram_tile<<<B_*28, 256, 0, stream>>>(w + OFF_Z, w + OFF_V, w + OFF_CP, w + OFF_H);
  k_redc<<<6400, 64, 0, stream>>>(w + OFF_Z, w + OFF_V, w + OFF_PSL, w + OFF_CP,
      w + OFF_COL, w + OFF_C);
  k_cumsum<<<32, 64, 0, stream>>>(w + OFF_Z, w + OFF_SZ, w + OFF_SV,
      w + OFF_COL, w + OFF_H, w + OFF_C,
      w + OFF_ZC, w + OFF_CM, w + OFF_CR, w + OFF_CCP);
  k_final<<<6400, 64, 0, stream>>>(w + OFF_NQ, w + OFF_Z, w + OFF_V, w + OFF_Q, w + OFF_ZC,
      w + OFF_PZL, w + OFF_MPS2, w + OFF_SNQ,
      w + OFF_CM, w + OFF_CR, w + OFF_CCP,
      w + OFF_PSL, w + OFF_PNAM,
      out, w + OFF_SYR, w + OFF_SY2R);
  k_std<<<1, 256, 0, stream>>>(w + OFF_SYR, w + OFF_SY2R, out);
}